// Round 10
// baseline (139.215 us; speedup 1.0000x reference)
//
#include <hip/hip_runtime.h>
#include <math.h>

#define N_PTS 262144
#define WIDTH 256
#define TSTRIDE 260   // dwords/tile-row: 1040 B = 16B-aligned; bank step 4/row

// fp32 Jacobi rotation on symmetric 3x3, updating eigenvector matrix columns
__device__ __forceinline__ void jrot(float &app, float &aqq, float &apq,
                                     float &arp, float &arq,
                                     float &vp0, float &vq0,
                                     float &vp1, float &vq1,
                                     float &vp2, float &vq2)
{
    float a = apq;
    if (fabsf(a) < 1e-20f) return;
    float theta = (aqq - app) / (2.0f * a);
    float tt = copysignf(1.0f, theta) / (fabsf(theta) + sqrtf(1.0f + theta * theta));
    float c = 1.0f / sqrtf(1.0f + tt * tt);
    float s = tt * c;
    app -= tt * a;
    aqq += tt * a;
    apq = 0.0f;
    float rp = arp, rq = arq;
    arp = c * rp - s * rq;
    arq = s * rp + c * rq;
    float t0p = vp0, t0q = vq0; vp0 = c * t0p - s * t0q; vq0 = s * t0p + c * t0q;
    float t1p = vp1, t1q = vq1; vp1 = c * t1p - s * t1q; vq1 = s * t1p + c * t1q;
    float t2p = vp2, t2q = vq2; vp2 = c * t2p - s * t2q; vq2 = s * t2p + c * t2q;
}

// Sequential-panel GEMV: block owns 256 consecutive rows (256 KB contiguous).
// 8 phases x 32 full rows (32 KB sequential per phase). Wave w handles
// k in [64w, 64w+64) for all 32 staged points (lanes 32..63 broadcast-
// duplicate); partials meet in part[]; the owning quarter-wave of phase p
// captures y into registers. 2 barriers/phase. 38 KB LDS -> 4 blocks/CU.
__global__ __launch_bounds__(256) void so3_kernel(
    const float* __restrict__ x,
    const float* __restrict__ fw,
    const float* __restrict__ fb,
    float* __restrict__ out)
{
    __shared__ float tile[32 * TSTRIDE];   // 33,280 B
    __shared__ float part[32 * 37];        //  4,736 B

    const int t    = threadIdx.x;
    const int lane = t & 63;
    const int wv   = __builtin_amdgcn_readfirstlane(t >> 6);   // 0..3
    const int r0   = blockIdx.x << 8;

    // staging map: instr i, thread t -> local float4 f = 256*i + (t&3)*64 + (t>>2)
    //  -> row = 4i + (t&3), col4 = t>>2.  Global: 4 coalesced 256B segments
    //  per wave-instr; LDS b128 writes ~2-way; contiguous 4 KB per instr.
    const int srow  = t & 3;
    const int scol4 = t >> 2;
    const float4* x4 = reinterpret_cast<const float4*>(x);
    const size_t bbase4 = (size_t)blockIdx.x * 16384;   // 256 rows * 64 f4

    float4 pre[8];
#pragma unroll
    for (int i = 0; i < 8; ++i)
        pre[i] = x4[bbase4 + 256 * i + srow * 64 + scol4];

    float y[9];
#pragma unroll
    for (int j = 0; j < 9; ++j) y[j] = 0.f;

    for (int p = 0; p < 8; ++p) {
        // stage prefetched rows (b128, 16B-aligned)
#pragma unroll
        for (int i = 0; i < 8; ++i)
            *reinterpret_cast<float4*>(
                &tile[(4 * i + srow) * TSTRIDE + (scol4 << 2)]) = pre[i];

        // issue next phase's sequential 32 KB; flies over this phase's compute
        if (p < 7) {
            const size_t nb = bbase4 + (size_t)(p + 1) * 2048;
#pragma unroll
            for (int i = 0; i < 8; ++i)
                pre[i] = x4[nb + 256 * i + srow * 64 + scol4];
        }
        __syncthreads();                    // tile ready; prev part consumed

        // wave wv: k-slice [64wv, 64wv+64) for point pt (upper half broadcasts)
        const int pt = lane & 31;
        float acc[9];
#pragma unroll
        for (int j = 0; j < 9; ++j) acc[j] = 0.f;
        const float* trow = &tile[pt * TSTRIDE + (wv << 6)];
#pragma unroll
        for (int q = 0; q < 16; ++q) {
            const float4 xv = *reinterpret_cast<const float4*>(trow + (q << 2));
            const int k = (wv << 6) + (q << 2);     // wave-uniform -> s_loads
            acc[0] = fmaf(xv.x, fw[0 * WIDTH + k], acc[0]);
            acc[1] = fmaf(xv.x, fw[1 * WIDTH + k], acc[1]);
            acc[2] = fmaf(xv.x, fw[2 * WIDTH + k], acc[2]);
            acc[3] = fmaf(xv.x, fw[3 * WIDTH + k], acc[3]);
            acc[4] = fmaf(xv.x, fw[4 * WIDTH + k], acc[4]);
            acc[5] = fmaf(xv.x, fw[5 * WIDTH + k], acc[5]);
            acc[6] = fmaf(xv.x, fw[6 * WIDTH + k], acc[6]);
            acc[7] = fmaf(xv.x, fw[7 * WIDTH + k], acc[7]);
            acc[8] = fmaf(xv.x, fw[8 * WIDTH + k], acc[8]);
#pragma unroll
            for (int j = 0; j < 9; ++j) acc[j] = fmaf(xv.y, fw[j * WIDTH + k + 1], acc[j]);
#pragma unroll
            for (int j = 0; j < 9; ++j) acc[j] = fmaf(xv.z, fw[j * WIDTH + k + 2], acc[j]);
#pragma unroll
            for (int j = 0; j < 9; ++j) acc[j] = fmaf(xv.w, fw[j * WIDTH + k + 3], acc[j]);
        }
        if (lane < 32) {                    // lower half writes (banks 5*pt: bijective)
#pragma unroll
            for (int j = 0; j < 9; ++j) part[pt * 37 + 9 * wv + j] = acc[j];
        }
        __syncthreads();                    // partials ready

        // owning quarter-wave of phase p captures y
        if ((p & 3) == wv && (p >> 2) == (lane >> 5)) {
            const int b = (lane & 31) * 37;
#pragma unroll
            for (int j = 0; j < 9; ++j)
                y[j] = part[b + j] + part[b + 9 + j]
                     + part[b + 18 + j] + part[b + 27 + j] + fb[j];
        }
    }

    // this thread's point: phase (wv + 4*(lane>>5)), row (lane&31)
    const int pidx = r0 + 32 * (wv + 4 * (lane >> 5)) + (lane & 31);

    // ---- fp32 3x3 special Procrustes:  R = U diag(1,1,det) V^T ----
    const float m00 = y[0], m01 = y[1], m02 = y[2];
    const float m10 = y[3], m11 = y[4], m12 = y[5];
    const float m20 = y[6], m21 = y[7], m22 = y[8];

    float a00 = m00*m00 + m10*m10 + m20*m20;
    float a01 = m00*m01 + m10*m11 + m20*m21;
    float a02 = m00*m02 + m10*m12 + m20*m22;
    float a11 = m01*m01 + m11*m11 + m21*m21;
    float a12 = m01*m02 + m11*m12 + m21*m22;
    float a22 = m02*m02 + m12*m12 + m22*m22;

    float v[3][3] = { {1,0,0}, {0,1,0}, {0,0,1} };

#pragma unroll
    for (int sw = 0; sw < 5; ++sw) {
        jrot(a00, a11, a01, a02, a12,
             v[0][0], v[0][1], v[1][0], v[1][1], v[2][0], v[2][1]);
        jrot(a00, a22, a02, a01, a12,
             v[0][0], v[0][2], v[1][0], v[1][2], v[2][0], v[2][2]);
        jrot(a11, a22, a12, a01, a02,
             v[0][1], v[0][2], v[1][1], v[1][2], v[2][1], v[2][2]);
    }

    float d0 = a00, d1 = a11, d2 = a22, tmp;
    if (d0 < d1) { tmp=d0; d0=d1; d1=tmp;
        tmp=v[0][0]; v[0][0]=v[0][1]; v[0][1]=tmp;
        tmp=v[1][0]; v[1][0]=v[1][1]; v[1][1]=tmp;
        tmp=v[2][0]; v[2][0]=v[2][1]; v[2][1]=tmp; }
    if (d0 < d2) { tmp=d0; d0=d2; d2=tmp;
        tmp=v[0][0]; v[0][0]=v[0][2]; v[0][2]=tmp;
        tmp=v[1][0]; v[1][0]=v[1][2]; v[1][2]=tmp;
        tmp=v[2][0]; v[2][0]=v[2][2]; v[2][2]=tmp; }
    if (d1 < d2) { tmp=d1; d1=d2; d2=tmp;
        tmp=v[0][1]; v[0][1]=v[0][2]; v[0][2]=tmp;
        tmp=v[1][1]; v[1][1]=v[1][2]; v[1][2]=tmp;
        tmp=v[2][1]; v[2][1]=v[2][2]; v[2][2]=tmp; }

    const float v1x = v[0][0], v1y = v[1][0], v1z = v[2][0];
    const float v2x = v[0][1], v2y = v[1][1], v2z = v[2][1];

    // u1 = normalize(M v1)
    float u1x = m00*v1x + m01*v1y + m02*v1z;
    float u1y = m10*v1x + m11*v1y + m12*v1z;
    float u1z = m20*v1x + m21*v1y + m22*v1z;
    float inv1 = 1.0f / (sqrtf(u1x*u1x + u1y*u1y + u1z*u1z) + 1e-30f);
    u1x *= inv1; u1y *= inv1; u1z *= inv1;

    // u2 = normalize(M v2 - (u1 . M v2) u1)
    float u2x = m00*v2x + m01*v2y + m02*v2z;
    float u2y = m10*v2x + m11*v2y + m12*v2z;
    float u2z = m20*v2x + m21*v2y + m22*v2z;
    const float d12 = u1x*u2x + u1y*u2y + u1z*u2z;
    u2x -= d12*u1x; u2y -= d12*u1y; u2z -= d12*u1z;
    float inv2 = 1.0f / (sqrtf(u2x*u2x + u2y*u2y + u2z*u2z) + 1e-30f);
    u2x *= inv2; u2y *= inv2; u2z *= inv2;

    // u3 = u1 x u2 ; v3 = v1 x v2
    const float u3x = u1y*u2z - u1z*u2y;
    const float u3y = u1z*u2x - u1x*u2z;
    const float u3z = u1x*u2y - u1y*u2x;
    const float v3x = v1y*v2z - v1z*v2y;
    const float v3y = v1z*v2x - v1x*v2z;
    const float v3z = v1x*v2y - v1y*v2x;

    float r[9];
    r[0] = u1x*v1x + u2x*v2x + u3x*v3x;
    r[1] = u1x*v1y + u2x*v2y + u3x*v3y;
    r[2] = u1x*v1z + u2x*v2z + u3x*v3z;
    r[3] = u1y*v1x + u2y*v2x + u3y*v3x;
    r[4] = u1y*v1y + u2y*v2y + u3y*v3y;
    r[5] = u1y*v1z + u2y*v2z + u3y*v3z;
    r[6] = u1z*v1x + u2z*v2x + u3z*v3x;
    r[7] = u1z*v1y + u2z*v2y + u3z*v3y;
    r[8] = u1z*v1z + u2z*v2z + u3z*v3z;

    float* o = out + (size_t)pidx * 9;
#pragma unroll
    for (int j = 0; j < 9; ++j) o[j] = r[j];
}

extern "C" void kernel_launch(void* const* d_in, const int* in_sizes, int n_in,
                              void* d_out, int out_size, void* d_ws, size_t ws_size,
                              hipStream_t stream) {
    const float* x  = (const float*)d_in[0];
    const float* fw = (const float*)d_in[1];
    const float* fb = (const float*)d_in[2];
    float* out = (float*)d_out;
    dim3 grid(N_PTS / 256), block(256);
    hipLaunchKernelGGL(so3_kernel, grid, block, 0, stream, x, fw, fb, out);
}

// Round 11
// 60.626 us; speedup vs baseline: 2.2963x; 2.2963x over previous
//
#include <hip/hip_runtime.h>
#include <math.h>

#define N_PTS 262144
#define WIDTH 256

// fp32 Jacobi rotation on symmetric 3x3, updating eigenvector matrix columns
__device__ __forceinline__ void jrot(float &app, float &aqq, float &apq,
                                     float &arp, float &arq,
                                     float &vp0, float &vq0,
                                     float &vp1, float &vq1,
                                     float &vp2, float &vq2)
{
    float a = apq;
    if (fabsf(a) < 1e-20f) return;
    float theta = (aqq - app) / (2.0f * a);
    float tt = copysignf(1.0f, theta) / (fabsf(theta) + sqrtf(1.0f + theta * theta));
    float c = 1.0f / sqrtf(1.0f + tt * tt);
    float s = tt * c;
    app -= tt * a;
    aqq += tt * a;
    apq = 0.0f;
    float rp = arp, rq = arq;
    arp = c * rp - s * rq;
    arq = s * rp + c * rq;
    float t0p = vp0, t0q = vq0; vp0 = c * t0p - s * t0q; vq0 = s * t0p + c * t0q;
    float t1p = vp1, t1q = vq1; vp1 = c * t1p - s * t1q; vq1 = s * t1p + c * t1q;
    float t2p = vp2, t2q = vq2; vp2 = c * t2p - s * t2q; vq2 = s * t2p + c * t2q;
}

// R6 structure (barrier-free private 64x33 tiles, conflict-free banks,
// wave-uniform k -> scalar W loads) + DEPTH-2 register prefetch:
// two 8xfloat4 buffers, statically unrolled 2-phase body. In-flight
// bytes per wave 8KB -> 16KB (tests the outstanding-miss-capacity theory).
__global__ __launch_bounds__(256, 4) void so3_kernel(
    const float* __restrict__ x,
    const float* __restrict__ fw,
    const float* __restrict__ fb,
    float* __restrict__ out)
{
    __shared__ float xs[4][64][33];     // 33.8 KB: 4 blocks/CU
    const int lane = threadIdx.x & 63;
    const int w    = threadIdx.x >> 6;
    const int r0   = (((blockIdx.x << 2) + w) << 6);   // wave's first point
    float (*tile)[33] = xs[w];

    const int a = lane >> 3;            // row sub-index 0..7
    const int b = lane & 7;             // float4 slot in row 0..7
    const float* xb = x + (size_t)r0 * WIDTH + (b << 2);

    float y[9];
#pragma unroll
    for (int j = 0; j < 9; ++j) y[j] = 0.f;

    float4 preA[8], preB[8];
    // prologue: prefetch chunks 0 (A) and 1 (B)
#pragma unroll
    for (int i = 0; i < 8; ++i) {
        const int row = (i << 3) + a;
        preA[i] = *reinterpret_cast<const float4*>(xb + (size_t)row * WIDTH);
    }
#pragma unroll
    for (int i = 0; i < 8; ++i) {
        const int row = (i << 3) + a;
        preB[i] = *reinterpret_cast<const float4*>(xb + (size_t)row * WIDTH + 32);
    }

#pragma unroll
    for (int kc = 0; kc < 8; kc += 2) {
        // ---- phase A: chunk kc ----
#pragma unroll
        for (int i = 0; i < 8; ++i) {
            const int row = (i << 3) + a;
            const int c   = b << 2;
            tile[row][c + 0] = preA[i].x;
            tile[row][c + 1] = preA[i].y;
            tile[row][c + 2] = preA[i].z;
            tile[row][c + 3] = preA[i].w;
        }
        if (kc + 2 < 8) {
            const int k0n = (kc + 2) << 5;
#pragma unroll
            for (int i = 0; i < 8; ++i) {
                const int row = (i << 3) + a;
                preA[i] = *reinterpret_cast<const float4*>(
                    xb + (size_t)row * WIDTH + k0n);
            }
        }
        {
            const int k0 = kc << 5;
#pragma unroll
            for (int kk = 0; kk < 32; ++kk) {
                const float xv = tile[lane][kk];   // bank (lane+kk)%32: free
                const int k = k0 + kk;             // uniform -> scalar s_loads
#pragma unroll
                for (int j = 0; j < 9; ++j)
                    y[j] = fmaf(xv, fw[j * WIDTH + k], y[j]);
            }
        }

        // ---- phase B: chunk kc+1 ----
#pragma unroll
        for (int i = 0; i < 8; ++i) {
            const int row = (i << 3) + a;
            const int c   = b << 2;
            tile[row][c + 0] = preB[i].x;
            tile[row][c + 1] = preB[i].y;
            tile[row][c + 2] = preB[i].z;
            tile[row][c + 3] = preB[i].w;
        }
        if (kc + 3 < 8) {
            const int k0n = (kc + 3) << 5;
#pragma unroll
            for (int i = 0; i < 8; ++i) {
                const int row = (i << 3) + a;
                preB[i] = *reinterpret_cast<const float4*>(
                    xb + (size_t)row * WIDTH + k0n);
            }
        }
        {
            const int k0 = (kc + 1) << 5;
#pragma unroll
            for (int kk = 0; kk < 32; ++kk) {
                const float xv = tile[lane][kk];
                const int k = k0 + kk;
#pragma unroll
                for (int j = 0; j < 9; ++j)
                    y[j] = fmaf(xv, fw[j * WIDTH + k], y[j]);
            }
        }
    }

#pragma unroll
    for (int j = 0; j < 9; ++j) y[j] += fb[j];

    // ---- fp32 3x3 special Procrustes:  R = U diag(1,1,det) V^T ----
    const float m00 = y[0], m01 = y[1], m02 = y[2];
    const float m10 = y[3], m11 = y[4], m12 = y[5];
    const float m20 = y[6], m21 = y[7], m22 = y[8];

    float a00 = m00*m00 + m10*m10 + m20*m20;
    float a01 = m00*m01 + m10*m11 + m20*m21;
    float a02 = m00*m02 + m10*m12 + m20*m22;
    float a11 = m01*m01 + m11*m11 + m21*m21;
    float a12 = m01*m02 + m11*m12 + m21*m22;
    float a22 = m02*m02 + m12*m12 + m22*m22;

    float v[3][3] = { {1,0,0}, {0,1,0}, {0,0,1} };

#pragma unroll
    for (int sw = 0; sw < 5; ++sw) {
        jrot(a00, a11, a01, a02, a12,
             v[0][0], v[0][1], v[1][0], v[1][1], v[2][0], v[2][1]);
        jrot(a00, a22, a02, a01, a12,
             v[0][0], v[0][2], v[1][0], v[1][2], v[2][0], v[2][2]);
        jrot(a11, a22, a12, a01, a02,
             v[0][1], v[0][2], v[1][1], v[1][2], v[2][1], v[2][2]);
    }

    float d0 = a00, d1 = a11, d2 = a22, tmp;
    if (d0 < d1) { tmp=d0; d0=d1; d1=tmp;
        tmp=v[0][0]; v[0][0]=v[0][1]; v[0][1]=tmp;
        tmp=v[1][0]; v[1][0]=v[1][1]; v[1][1]=tmp;
        tmp=v[2][0]; v[2][0]=v[2][1]; v[2][1]=tmp; }
    if (d0 < d2) { tmp=d0; d0=d2; d2=tmp;
        tmp=v[0][0]; v[0][0]=v[0][2]; v[0][2]=tmp;
        tmp=v[1][0]; v[1][0]=v[1][2]; v[1][2]=tmp;
        tmp=v[2][0]; v[2][0]=v[2][2]; v[2][2]=tmp; }
    if (d1 < d2) { tmp=d1; d1=d2; d2=tmp;
        tmp=v[0][1]; v[0][1]=v[0][2]; v[0][2]=tmp;
        tmp=v[1][1]; v[1][1]=v[1][2]; v[1][2]=tmp;
        tmp=v[2][1]; v[2][1]=v[2][2]; v[2][2]=tmp; }

    const float v1x = v[0][0], v1y = v[1][0], v1z = v[2][0];
    const float v2x = v[0][1], v2y = v[1][1], v2z = v[2][1];

    // u1 = normalize(M v1)
    float u1x = m00*v1x + m01*v1y + m02*v1z;
    float u1y = m10*v1x + m11*v1y + m12*v1z;
    float u1z = m20*v1x + m21*v1y + m22*v1z;
    float inv1 = 1.0f / (sqrtf(u1x*u1x + u1y*u1y + u1z*u1z) + 1e-30f);
    u1x *= inv1; u1y *= inv1; u1z *= inv1;

    // u2 = normalize(M v2 - (u1 . M v2) u1)
    float u2x = m00*v2x + m01*v2y + m02*v2z;
    float u2y = m10*v2x + m11*v2y + m12*v2z;
    float u2z = m20*v2x + m21*v2y + m22*v2z;
    const float d12 = u1x*u2x + u1y*u2y + u1z*u2z;
    u2x -= d12*u1x; u2y -= d12*u1y; u2z -= d12*u1z;
    float inv2 = 1.0f / (sqrtf(u2x*u2x + u2y*u2y + u2z*u2z) + 1e-30f);
    u2x *= inv2; u2y *= inv2; u2z *= inv2;

    // u3 = u1 x u2 ; v3 = v1 x v2
    const float u3x = u1y*u2z - u1z*u2y;
    const float u3y = u1z*u2x - u1x*u2z;
    const float u3z = u1x*u2y - u1y*u2x;
    const float v3x = v1y*v2z - v1z*v2y;
    const float v3y = v1z*v2x - v1x*v2z;
    const float v3z = v1x*v2y - v1y*v2x;

    float r[9];
    r[0] = u1x*v1x + u2x*v2x + u3x*v3x;
    r[1] = u1x*v1y + u2x*v2y + u3x*v3y;
    r[2] = u1x*v1z + u2x*v2z + u3x*v3z;
    r[3] = u1y*v1x + u2y*v2x + u3y*v3x;
    r[4] = u1y*v1y + u2y*v2y + u3y*v3y;
    r[5] = u1y*v1z + u2y*v2z + u3y*v3z;
    r[6] = u1z*v1x + u2z*v2x + u3z*v3x;
    r[7] = u1z*v1y + u2z*v2y + u3z*v3y;
    r[8] = u1z*v1z + u2z*v2z + u3z*v3z;

    float* o = out + (size_t)(r0 + lane) * 9;
#pragma unroll
    for (int j = 0; j < 9; ++j) o[j] = r[j];
}

extern "C" void kernel_launch(void* const* d_in, const int* in_sizes, int n_in,
                              void* d_out, int out_size, void* d_ws, size_t ws_size,
                              hipStream_t stream) {
    const float* x  = (const float*)d_in[0];
    const float* fw = (const float*)d_in[1];
    const float* fb = (const float*)d_in[2];
    float* out = (float*)d_out;
    dim3 grid(N_PTS / 256), block(256);   // 4 waves/block, 64 points/wave
    hipLaunchKernelGGL(so3_kernel, grid, block, 0, stream, x, fw, fb, out);
}

// Round 12
// 60.243 us; speedup vs baseline: 2.3109x; 1.0064x over previous
//
#include <hip/hip_runtime.h>
#include <math.h>

#define N_PTS 262144
#define WIDTH 256

// fp32 Jacobi rotation on symmetric 3x3, updating eigenvector matrix columns
__device__ __forceinline__ void jrot(float &app, float &aqq, float &apq,
                                     float &arp, float &arq,
                                     float &vp0, float &vq0,
                                     float &vp1, float &vq1,
                                     float &vp2, float &vq2)
{
    float a = apq;
    if (fabsf(a) < 1e-20f) return;
    float theta = (aqq - app) / (2.0f * a);
    float tt = copysignf(1.0f, theta) / (fabsf(theta) + sqrtf(1.0f + theta * theta));
    float c = 1.0f / sqrtf(1.0f + tt * tt);
    float s = tt * c;
    app -= tt * a;
    aqq += tt * a;
    apq = 0.0f;
    float rp = arp, rq = arq;
    arp = c * rp - s * rq;
    arq = s * rp + c * rq;
    float t0p = vp0, t0q = vq0; vp0 = c * t0p - s * t0q; vq0 = s * t0p + c * t0q;
    float t1p = vp1, t1q = vq1; vp1 = c * t1p - s * t1q; vq1 = s * t1p + c * t1q;
    float t2p = vp2, t2q = vq2; vp2 = c * t2p - s * t2q; vq2 = s * t2p + c * t2q;
}

// R11 structure + DEPTH-3 register prefetch (buffers A,B,C rotate across
// 8 statically-unrolled phases; all indexing compile-time). In-flight
// bytes/wave 16KB -> 24KB. Barrier-free private tiles, conflict-free banks,
// wave-uniform k -> scalar W loads, fp32 Procrustes epilogue.
__global__ __launch_bounds__(256, 4) void so3_kernel(
    const float* __restrict__ x,
    const float* __restrict__ fw,
    const float* __restrict__ fb,
    float* __restrict__ out)
{
    __shared__ float xs[4][64][33];     // 33.8 KB: 4 blocks/CU
    const int lane = threadIdx.x & 63;
    const int w    = threadIdx.x >> 6;
    const int r0   = (((blockIdx.x << 2) + w) << 6);   // wave's first point
    float (*tile)[33] = xs[w];

    const int a = lane >> 3;            // row sub-index 0..7
    const int b = lane & 7;             // float4 slot in row 0..7
    const float* xb = x + (size_t)r0 * WIDTH + (b << 2);

    float y[9];
#pragma unroll
    for (int j = 0; j < 9; ++j) y[j] = 0.f;

    float4 preA[8], preB[8], preC[8];

#define FETCH(BUF, KC)                                                        \
    _Pragma("unroll")                                                         \
    for (int i = 0; i < 8; ++i) {                                             \
        const int row = (i << 3) + a;                                         \
        BUF[i] = *reinterpret_cast<const float4*>(                            \
            xb + (size_t)row * WIDTH + ((KC) << 5));                          \
    }

#define STAGE(BUF)                                                            \
    _Pragma("unroll")                                                         \
    for (int i = 0; i < 8; ++i) {                                             \
        const int row = (i << 3) + a;                                         \
        const int c   = b << 2;                                               \
        tile[row][c + 0] = BUF[i].x;                                          \
        tile[row][c + 1] = BUF[i].y;                                          \
        tile[row][c + 2] = BUF[i].z;                                          \
        tile[row][c + 3] = BUF[i].w;                                          \
    }

#define COMPUTE(KC)                                                           \
    {                                                                         \
        const int k0 = (KC) << 5;                                             \
        _Pragma("unroll")                                                     \
        for (int kk = 0; kk < 32; ++kk) {                                     \
            const float xv = tile[lane][kk];                                  \
            const int k = k0 + kk;                                            \
            _Pragma("unroll")                                                 \
            for (int j = 0; j < 9; ++j)                                       \
                y[j] = fmaf(xv, fw[j * WIDTH + k], y[j]);                     \
        }                                                                     \
    }

    // prologue: 3 chunks in flight (24 KB/wave)
    FETCH(preA, 0)
    FETCH(preB, 1)
    FETCH(preC, 2)

    STAGE(preA)  FETCH(preA, 3)  COMPUTE(0)
    STAGE(preB)  FETCH(preB, 4)  COMPUTE(1)
    STAGE(preC)  FETCH(preC, 5)  COMPUTE(2)
    STAGE(preA)  FETCH(preA, 6)  COMPUTE(3)
    STAGE(preB)  FETCH(preB, 7)  COMPUTE(4)
    STAGE(preC)               COMPUTE(5)
    STAGE(preA)               COMPUTE(6)
    STAGE(preB)               COMPUTE(7)

#undef FETCH
#undef STAGE
#undef COMPUTE

#pragma unroll
    for (int j = 0; j < 9; ++j) y[j] += fb[j];

    // ---- fp32 3x3 special Procrustes:  R = U diag(1,1,det) V^T ----
    const float m00 = y[0], m01 = y[1], m02 = y[2];
    const float m10 = y[3], m11 = y[4], m12 = y[5];
    const float m20 = y[6], m21 = y[7], m22 = y[8];

    float a00 = m00*m00 + m10*m10 + m20*m20;
    float a01 = m00*m01 + m10*m11 + m20*m21;
    float a02 = m00*m02 + m10*m12 + m20*m22;
    float a11 = m01*m01 + m11*m11 + m21*m21;
    float a12 = m01*m02 + m11*m12 + m21*m22;
    float a22 = m02*m02 + m12*m12 + m22*m22;

    float v[3][3] = { {1,0,0}, {0,1,0}, {0,0,1} };

#pragma unroll
    for (int sw = 0; sw < 5; ++sw) {
        jrot(a00, a11, a01, a02, a12,
             v[0][0], v[0][1], v[1][0], v[1][1], v[2][0], v[2][1]);
        jrot(a00, a22, a02, a01, a12,
             v[0][0], v[0][2], v[1][0], v[1][2], v[2][0], v[2][2]);
        jrot(a11, a22, a12, a01, a02,
             v[0][1], v[0][2], v[1][1], v[1][2], v[2][1], v[2][2]);
    }

    float d0 = a00, d1 = a11, d2 = a22, tmp;
    if (d0 < d1) { tmp=d0; d0=d1; d1=tmp;
        tmp=v[0][0]; v[0][0]=v[0][1]; v[0][1]=tmp;
        tmp=v[1][0]; v[1][0]=v[1][1]; v[1][1]=tmp;
        tmp=v[2][0]; v[2][0]=v[2][1]; v[2][1]=tmp; }
    if (d0 < d2) { tmp=d0; d0=d2; d2=tmp;
        tmp=v[0][0]; v[0][0]=v[0][2]; v[0][2]=tmp;
        tmp=v[1][0]; v[1][0]=v[1][2]; v[1][2]=tmp;
        tmp=v[2][0]; v[2][0]=v[2][2]; v[2][2]=tmp; }
    if (d1 < d2) { tmp=d1; d1=d2; d2=tmp;
        tmp=v[0][1]; v[0][1]=v[0][2]; v[0][2]=tmp;
        tmp=v[1][1]; v[1][1]=v[1][2]; v[1][2]=tmp;
        tmp=v[2][1]; v[2][1]=v[2][2]; v[2][2]=tmp; }

    const float v1x = v[0][0], v1y = v[1][0], v1z = v[2][0];
    const float v2x = v[0][1], v2y = v[1][1], v2z = v[2][1];

    // u1 = normalize(M v1)
    float u1x = m00*v1x + m01*v1y + m02*v1z;
    float u1y = m10*v1x + m11*v1y + m12*v1z;
    float u1z = m20*v1x + m21*v1y + m22*v1z;
    float inv1 = 1.0f / (sqrtf(u1x*u1x + u1y*u1y + u1z*u1z) + 1e-30f);
    u1x *= inv1; u1y *= inv1; u1z *= inv1;

    // u2 = normalize(M v2 - (u1 . M v2) u1)
    float u2x = m00*v2x + m01*v2y + m02*v2z;
    float u2y = m10*v2x + m11*v2y + m12*v2z;
    float u2z = m20*v2x + m21*v2y + m22*v2z;
    const float d12 = u1x*u2x + u1y*u2y + u1z*u2z;
    u2x -= d12*u1x; u2y -= d12*u1y; u2z -= d12*u1z;
    float inv2 = 1.0f / (sqrtf(u2x*u2x + u2y*u2y + u2z*u2z) + 1e-30f);
    u2x *= inv2; u2y *= inv2; u2z *= inv2;

    // u3 = u1 x u2 ; v3 = v1 x v2
    const float u3x = u1y*u2z - u1z*u2y;
    const float u3y = u1z*u2x - u1x*u2z;
    const float u3z = u1x*u2y - u1y*u2x;
    const float v3x = v1y*v2z - v1z*v2y;
    const float v3y = v1z*v2x - v1x*v2z;
    const float v3z = v1x*v2y - v1y*v2x;

    float r[9];
    r[0] = u1x*v1x + u2x*v2x + u3x*v3x;
    r[1] = u1x*v1y + u2x*v2y + u3x*v3y;
    r[2] = u1x*v1z + u2x*v2z + u3x*v3z;
    r[3] = u1y*v1x + u2y*v2x + u3y*v3x;
    r[4] = u1y*v1y + u2y*v2y + u3y*v3y;
    r[5] = u1y*v1z + u2y*v2z + u3y*v3z;
    r[6] = u1z*v1x + u2z*v2x + u3z*v3x;
    r[7] = u1z*v1y + u2z*v2y + u3z*v3y;
    r[8] = u1z*v1z + u2z*v2z + u3z*v3z;

    float* o = out + (size_t)(r0 + lane) * 9;
#pragma unroll
    for (int j = 0; j < 9; ++j) o[j] = r[j];
}

extern "C" void kernel_launch(void* const* d_in, const int* in_sizes, int n_in,
                              void* d_out, int out_size, void* d_ws, size_t ws_size,
                              hipStream_t stream) {
    const float* x  = (const float*)d_in[0];
    const float* fw = (const float*)d_in[1];
    const float* fb = (const float*)d_in[2];
    float* out = (float*)d_out;
    dim3 grid(N_PTS / 256), block(256);   // 4 waves/block, 64 points/wave
    hipLaunchKernelGGL(so3_kernel, grid, block, 0, stream, x, fw, fb, out);
}